// Round 9
// baseline (283.957 us; speedup 1.0000x reference)
//
#include <hip/hip_runtime.h>

typedef __attribute__((ext_vector_type(8))) __bf16 bf16x8;
typedef __attribute__((ext_vector_type(4))) float f32x4;

constexpr int BB = 16, NN = 906, CC = 768, HH = 12, MM1 = 513;
constexpr int MTOK = BB * NN;      // 14496 tokens
constexpr int TOKC = MTOK * CC;    // 11132928 elements

#define MFMA16(a, b, c) __builtin_amdgcn_mfma_f32_16x16x32_bf16((a), (b), (c), 0, 0, 0)

__device__ __forceinline__ void glds16(const void* g, void* l) {
  __builtin_amdgcn_global_load_lds(
      (const __attribute__((address_space(1))) void*)g,
      (__attribute__((address_space(3))) void*)l, 16, 0, 0);
}

__device__ __forceinline__ unsigned pack2(float a, float b) {
  unsigned short ua = __builtin_bit_cast(unsigned short, (__bf16)a);
  unsigned short ub = __builtin_bit_cast(unsigned short, (__bf16)b);
  return (unsigned)ua | ((unsigned)ub << 16);
}

union U8 { unsigned u[4]; bf16x8 v; };

// ---------------- convert x (fp32 -> bf16) ----------------
__global__ __launch_bounds__(256) void cvt_x_kernel(const float* __restrict__ x,
                                                    __bf16* __restrict__ xb) {
  long i = (long)blockIdx.x * 256 + threadIdx.x;
  const float4* p = (const float4*)x + i * 2;
  float4 a = p[0], b = p[1];
  bf16x8 o;
  o[0] = (__bf16)a.x; o[1] = (__bf16)a.y; o[2] = (__bf16)a.z; o[3] = (__bf16)a.w;
  o[4] = (__bf16)b.x; o[5] = (__bf16)b.y; o[6] = (__bf16)b.z; o[7] = (__bf16)b.w;
  *(bf16x8*)(xb + i * 8) = o;
}

// ---------------- transpose + convert weights: Wt[n][k] = W[k][n] ----------------
__global__ __launch_bounds__(256) void cvt_w_kernel(
    const float* __restrict__ W0, const float* __restrict__ W1,
    const float* __restrict__ W2, const float* __restrict__ W3,
    const float* __restrict__ W4, __bf16* __restrict__ out) {
  __shared__ float t[32][33];
  int z = blockIdx.z;
  const float* src = z == 0 ? W0 : z == 1 ? W1 : z == 2 ? W2 : z == 3 ? W3 : W4;
  __bf16* dst = out + (size_t)z * CC * CC;
  int x0 = blockIdx.x * 32, y0 = blockIdx.y * 32;
  int tx = threadIdx.x & 31, ty = threadIdx.x >> 5;  // ty 0..7
#pragma unroll
  for (int i = 0; i < 4; ++i)
    t[ty + i * 8][tx] = src[(size_t)(y0 + ty + i * 8) * CC + x0 + tx];
  __syncthreads();
#pragma unroll
  for (int i = 0; i < 4; ++i)
    dst[(size_t)(x0 + ty + i * 8) * CC + y0 + tx] = (__bf16)t[tx][ty + i * 8];
}

// ============ 256x256xK 8-phase QKV GEMM (m201 template, correct port) ============
// 8 waves (2M x 4N), wave tile 128x64 (acc[8][4] f32x4). LDS 128 KB = 2buf x
// (A[256][64] + B[256][64]), swizzled (src col ^= row&7, linear dest, swz read).
// Phase = { ds_reads (pre-barrier!); stage one half-tile (2 glds/thread);
//           s_barrier; lgkmcnt(0); setprio1; 16 MFMA; setprio0; [vmcnt@P4/P8];
//           s_barrier }.
// Freedom points: B-halves free after P1 (all B read in P1); A-halves free after
// P3 (each wm-wave re-reads its A-stripe at P1 and P3). Stage rotation honors
// this: P1:(t+1).A1  P2:(t+2).B0  P3:(t+2).B1  P4:(t+2).A0  P5:(t+2).A1
// P6:(t+3).B0  P7:(t+3).B1  P8:(t+3).A0.
// Gates: vmcnt(6) at P4 (tile t+1 ready before P5 reads) and P8 (tile t+2 ready
// before next-P1 reads) = 2 loads x 3 half-tiles in flight. Never 0 except tail.
#define BAR   asm volatile("s_barrier" ::: "memory")
#define LGKM0 asm volatile("s_waitcnt lgkmcnt(0)" ::: "memory")
#define VM6   asm volatile("s_waitcnt vmcnt(6)" ::: "memory")
#define VM0   asm volatile("s_waitcnt vmcnt(0)" ::: "memory")

__global__ __launch_bounds__(512, 2) void gemm_qkv256(
    const __bf16* __restrict__ Xb, const __bf16* __restrict__ WT,
    __bf16* __restrict__ Qb, __bf16* __restrict__ Kb,
    __bf16* __restrict__ VAb, __bf16* __restrict__ VVb) {
  __shared__ alignas(16) __bf16 LA[2][16384];
  __shared__ alignas(16) __bf16 LB[2][16384];

  const int tid = threadIdx.x;
  const int l = tid & 63, w = tid >> 6;
  const int l15 = l & 15, hi = l >> 4;
  const int wm = w >> 2, wn = w & 3;
  const int nt = blockIdx.x, mt = blockIdx.y;
  const int m0 = mt * 256;
  const int wi = nt / 3, nc = (nt % 3) * 256;
  const __bf16* bt = WT + (size_t)wi * (CC * CC) + (size_t)nc * CC;

  // staging map: thread covers 4 row-groups (j*64+srow); half h = groups {2h,2h+1}
  const int srow = tid >> 3, sslot = tid & 7;
  const __bf16* pA[4]; const __bf16* pB[4]; int ldst[4];
#pragma unroll
  for (int j = 0; j < 4; ++j) {
    int row = j * 64 + srow;
    int co = (sslot ^ (row & 7)) * 8;
    int arow = m0 + row; arow = arow < MTOK ? arow : MTOK - 1;
    pA[j] = Xb + (size_t)arow * CC + co;
    pB[j] = bt + (size_t)row * CC + co;
    ldst[j] = row * 64 + sslot * 8;
  }

  f32x4 acc[8][4] = {};
  bf16x8 af[4][2], bg[4][2];

#define SGA(d, h)                                                              \
  { glds16(pA[2*(h)],   &LA[d][ldst[2*(h)]]);   pA[2*(h)]   += 64;             \
    glds16(pA[2*(h)+1], &LA[d][ldst[2*(h)+1]]); pA[2*(h)+1] += 64; }
#define SGB(d, h)                                                              \
  { glds16(pB[2*(h)],   &LB[d][ldst[2*(h)]]);   pB[2*(h)]   += 64;             \
    glds16(pB[2*(h)+1], &LB[d][ldst[2*(h)+1]]); pB[2*(h)+1] += 64; }
#define RDA(d, mh)                                                             \
  _Pragma("unroll") for (int fm = 0; fm < 4; ++fm) {                           \
    int row = wm * 128 + (mh) * 64 + fm * 16 + l15;                            \
    _Pragma("unroll") for (int kk = 0; kk < 2; ++kk)                           \
      af[fm][kk] = *(const bf16x8*)(&LA[d][row * 64 +                          \
                                           (((kk * 4 + hi) ^ (row & 7)) * 8)]);\
  }
#define RDB(d)                                                                 \
  _Pragma("unroll") for (int fn = 0; fn < 4; ++fn) {                           \
    int row = wn * 64 + fn * 16 + l15;                                         \
    _Pragma("unroll") for (int kk = 0; kk < 2; ++kk)                           \
      bg[fn][kk] = *(const bf16x8*)(&LB[d][row * 64 +                          \
                                           (((kk * 4 + hi) ^ (row & 7)) * 8)]);\
  }
#define MM(qm, qn)                                                             \
  __builtin_amdgcn_s_setprio(1);                                               \
  _Pragma("unroll") for (int fm = 0; fm < 4; ++fm)                             \
  _Pragma("unroll") for (int fl = 0; fl < 2; ++fl)                             \
  _Pragma("unroll") for (int kk = 0; kk < 2; ++kk)                             \
    acc[(qm)*4+fm][(qn)*2+fl] =                                                \
        MFMA16(af[fm][kk], bg[(qn)*2+fl][kk], acc[(qm)*4+fm][(qn)*2+fl]);      \
  __builtin_amdgcn_s_setprio(0);

  // prologue: t0 fully (B0,B1,A0,A1), t1 all but A1 (B0,B1,A0); gate t0
  SGB(0, 0); SGB(0, 1); SGA(0, 0); SGA(0, 1);   // t0: 8 loads
  SGB(1, 0); SGB(1, 1); SGA(1, 0);              // t1: 6 loads
  VM6;                                          // retire t0's 8; t1's 6 in flight
  BAR;

#pragma unroll
  for (int ti = 0; ti < 6; ++ti) {
    const bool last = (ti == 5);
    // P1: reads t(buf0) A-half(wm,0) + all B; stage (t+1).A1
    RDA(0, 0); RDB(0);
    SGA(1, 1);
    BAR; LGKM0; MM(0, 0); BAR;
    // P2: stage (t+2).B0
    if (!last) SGB(0, 0);
    BAR; LGKM0; MM(0, 1); BAR;
    // P3: reads A-half(wm,1); stage (t+2).B1
    RDA(0, 1);
    if (!last) SGB(0, 1);
    BAR; LGKM0; MM(1, 0); BAR;
    // P4: stage (t+2).A0; gate t+1 after MFMA
    if (!last) SGA(0, 0);
    BAR; LGKM0; MM(1, 1);
    if (!last) { VM6; } else { VM0; }
    BAR;
    // P5: reads t+1(buf1) A-half0 + B; stage (t+2).A1
    RDA(1, 0); RDB(1);
    if (!last) SGA(0, 1);
    BAR; LGKM0; MM(0, 0); BAR;
    // P6: stage (t+3).B0
    if (!last) SGB(1, 0);
    BAR; LGKM0; MM(0, 1); BAR;
    // P7: reads A-half1; stage (t+3).B1
    RDA(1, 1);
    if (!last) SGB(1, 1);
    BAR; LGKM0; MM(1, 0); BAR;
    // P8: stage (t+3).A0; gate t+2
    if (!last) SGA(1, 0);
    BAR; LGKM0; MM(1, 1);
    if (!last) VM6;
    BAR;
  }
#undef SGA
#undef SGB
#undef RDA
#undef RDB
#undef MM

  // epilogue: wave owns 128x64 at (wm*128, wn*64); col range = one head
  const int hq = (nt % 3) * 4 + wn;
  const float qs = (wi == 0) ? 0.1803368801f : 1.0f;  // 0.125 * log2(e)
  const int t00 = m0 + wm * 128 + hi * 4;
#pragma unroll
  for (int fm = 0; fm < 8; ++fm) {
    int tk = t00 + fm * 16;
    if (tk >= MTOK) continue;
    int b = tk / NN;
    int n = tk - b * NN;
#pragma unroll
    for (int r = 0; r < 4; ++r) {
      if (tk + r >= MTOK) continue;
      int nn = n + r, bb = b;
      if (nn >= NN) { nn -= NN; bb += 1; }
      size_t bhd = (size_t)bb * HH + hq;
#pragma unroll
      for (int fn = 0; fn < 4; ++fn) {
        int dd = fn * 16 + l15;
        __bf16 bv = (__bf16)(acc[fm][fn][r] * qs);
        if (wi == 0)      Qb[(bhd * NN + nn) * 64 + dd] = bv;
        else if (wi == 1) Kb[(bhd * NN + nn) * 64 + dd] = bv;
        else if (wi == 2) ((nn < MM1) ? VAb : VVb)[(bhd * 64 + dd) * NN + nn] = bv;
        else              ((nn < MM1) ? VVb : VAb)[(bhd * 64 + dd) * NN + nn] = bv;
      }
    }
  }
}

// -- Schedule-B 128x128x768 GEMM mainloop (kept for gemm_out) --
__device__ __forceinline__ void gemm_core_db2(const __bf16* __restrict__ A,
                                              const __bf16* __restrict__ Bt,
                                              __bf16* __restrict__ L,
                                              int m0, int M, f32x4 acc[4][4]) {
  const int tid = threadIdx.x;
  const int w = tid >> 6, l = tid & 63;
  const int l15 = l & 15, hi = l >> 4;
  const int wr = (w >> 1) * 64, wc = (w & 1) * 64;
  const int srow = l >> 3, sslot = l & 7;

  const __bf16* ga[4]; const __bf16* gb[4]; int lofs[4];
#pragma unroll
  for (int rr = 0; rr < 4; ++rr) {
    int row = rr * 32 + w * 8 + srow;
    int co = (sslot ^ (row & 7)) * 8;
    int arow = m0 + row; arow = arow < M ? arow : M - 1;
    ga[rr] = A + (size_t)arow * CC + co;
    gb[rr] = Bt + (size_t)row * CC + co;
    lofs[rr] = row * 64 + sslot * 8;
  }

#define STAGE_(buf)                                                            \
  {                                                                            \
    _Pragma("unroll") for (int rr = 0; rr < 4; ++rr) {                         \
      glds16(ga[rr], L + (buf) * 16384 + lofs[rr]);                            \
      glds16(gb[rr], L + (buf) * 16384 + 8192 + lofs[rr]);                     \
      ga[rr] += 64; gb[rr] += 64;                                              \
    }                                                                          \
  }

#define COMP_(buf)                                                             \
  {                                                                            \
    _Pragma("unroll") for (int kks = 0; kks < 2; ++kks) {                      \
      bf16x8 af[4], bfr[4];                                                    \
      _Pragma("unroll") for (int mf = 0; mf < 4; ++mf) {                       \
        int rowa = wr + mf * 16 + l15;                                         \
        af[mf] = *(const bf16x8*)(L + (buf) * 16384 + rowa * 64 +              \
                                  (((kks * 4 + hi) ^ (rowa & 7)) * 8));        \
      }                                                                        \
      _Pragma("unroll") for (int nf = 0; nf < 4; ++nf) {                       \
        int rowb = wc + nf * 16 + l15;                                         \
        bfr[nf] = *(const bf16x8*)(L + (buf) * 16384 + 8192 + rowb * 64 +      \
                                   (((kks * 4 + hi) ^ (rowb & 7)) * 8));       \
      }                                                                        \
      __builtin_amdgcn_s_setprio(1);                                           \
      _Pragma("unroll") for (int mf = 0; mf < 4; ++mf)                         \
          _Pragma("unroll") for (int nf = 0; nf < 4; ++nf)                     \
              acc[mf][nf] = MFMA16(af[mf], bfr[nf], acc[mf][nf]);              \
      __builtin_amdgcn_s_setprio(0);                                           \
    }                                                                          \
  }

  STAGE_(0);  // tile 0 -> 8 loads in flight

#pragma unroll
  for (int t = 0; t < 12; ++t) {
    if (t < 11) {
      STAGE_((t + 1) & 1);  // now 16 in flight
      asm volatile("s_waitcnt vmcnt(8)" ::: "memory");  // retire tile t only
    } else {
      asm volatile("s_waitcnt vmcnt(0)" ::: "memory");
    }
    asm volatile("s_barrier" ::: "memory");
    COMP_(t & 1);
    asm volatile("s_barrier" ::: "memory");  // close reads before next overwrite
  }
#undef STAGE_
#undef COMP_
}

// ---------------- flash attention, swapped-QK^T, UNNORMALIZED softmax ----------------
__global__ __launch_bounds__(256, 2) void attn_kernel(
    const __bf16* __restrict__ Q, const __bf16* __restrict__ K,
    const __bf16* __restrict__ VA, const __bf16* __restrict__ VV,
    __bf16* __restrict__ AO) {
  __shared__ alignas(16) __bf16 K_lds[2][64 * 64];
  __shared__ alignas(16) __bf16 V_lds[2][64 * 64];  // [dd][key]

  const int tid = threadIdx.x;
  const int w = tid >> 6, l = tid & 63;
  const int l15 = l & 15, hi = l >> 4;
  const int bh = blockIdx.y, tile = blockIdx.x;

  int q0, qn; bool mod1;
  if (tile < 9) { q0 = tile * 64; qn = min(64, MM1 - q0); mod1 = true; }
  else { q0 = MM1 + (tile - 9) * 64; qn = min(64, NN - q0); mod1 = false; }

  const __bf16* qp = Q + (size_t)bh * NN * 64;
  const __bf16* kp = K + (size_t)bh * NN * 64;
  const __bf16* vp = (mod1 ? VA : VV) + (size_t)bh * 64 * NN;

  int qrow = q0 + w * 16 + l15; qrow = qrow < NN ? qrow : NN - 1;
  bf16x8 qf0 = *(const bf16x8*)(qp + (size_t)qrow * 64 + hi * 8);
  bf16x8 qf1 = *(const bf16x8*)(qp + (size_t)qrow * 64 + 32 + hi * 8);

  f32x4 Of[4] = {};
  float l_run = 0.f;

  const int srow = l >> 3, sslot = l & 7;
  auto stage = [&](int kt, int buf) {
    int k0s = kt * 64;
#pragma unroll
    for (int rr = 0; rr < 2; ++rr) {
      int row = rr * 32 + w * 8 + srow;
      int krow = k0s + row; krow = krow < NN ? krow : NN - 1;  // dup key, masked
      glds16(kp + (size_t)krow * 64 + ((sslot ^ (row & 7)) * 8),
             &K_lds[buf][row * 64 + sslot * 8]);
      int vcol = k0s + ((sslot ^ (row & 7)) * 8);  // tail overrun: P=0 for those keys
      glds16(vp + (size_t)row * NN + vcol, &V_lds[buf][row * 64 + sslot * 8]);
    }
  };

  const bool ofirst = ((hi & 1) == 0);
  auto tilecomp = [&](const __bf16* Kb, const __bf16* Vb, bool maskTail) {
    f32x4 sa[4] = {};
    __builtin_amdgcn_s_setprio(1);
#pragma unroll
    for (int kks = 0; kks < 2; ++kks) {
#pragma unroll
      for (int f = 0; f < 4; ++f) {
        int rk = f * 16 + l15;
        bf16x8 kf = *(const bf16x8*)(Kb + rk * 64 + (((kks * 4 + hi) ^ (rk & 7)) * 8));
        sa[f] = MFMA16(kf, (kks ? qf1 : qf0), sa[f]);
      }
    }
    __builtin_amdgcn_s_setprio(0);

    if (maskTail) {
#pragma unroll
      for (int f = 0; f < 4; ++f) {
        int keyb = 896 + f * 16 + hi * 4;
#pragma unroll
        for (int r = 0; r < 4; ++r)
          if (keyb + r >= NN) sa[f][r] = -1e30f;
      }
    }

    float sl = 0.f;
#pragma unroll
    for (int f = 0; f < 4; ++f)
#pragma unroll
      for (int r = 0; r < 4; ++r) {
        sa[f][r] = __builtin_amdgcn_exp2f(sa[f][r]);
        sl += sa[f][r];
      }
    sl += __shfl_xor(sl, 16);
    sl += __shfl_xor(sl, 32);
    l_run += sl;

#pragma unroll
    for (int c = 0; c < 2; ++c) {
      unsigned p00 = pack2(sa[c * 2][0], sa[c * 2][1]);
      unsigned p01 = pack2(sa[c * 2][2], sa[c * 2][3]);
      unsigned p10 = pack2(sa[c * 2 + 1][0], sa[c * 2 + 1][1]);
      unsigned p11 = pack2(sa[c * 2 + 1][2], sa[c * 2 + 1][3]);
      unsigned own0 = (hi & 1) ? p10 : p00;
      unsigned own1 = (hi & 1) ? p11 : p01;
      unsigned snd0 = (hi & 1) ? p00 : p10;
      unsigned snd1 = (hi & 1) ? p01 : p11;
      unsigned rcv0 = __shfl_xor(snd0, 16);
      unsigned rcv1 = __shfl_xor(snd1, 16);
      U8 pu;
      pu.u[0] = ofirst ? own0 : rcv0;
      pu.u[1] = ofirst ? own1 : rcv1;
      pu.u[2] = ofirst ? rcv0 : own0;
      pu.u[3] = ofirst ? rcv1 : own1;
      const int slotbase = c * 4 + (hi & 1) * 2 + (hi >> 1);  // V octet slot
      __builtin_amdgcn_s_setprio(1);
#pragma unroll
      for (int fd = 0; fd < 4; ++fd) {
        int vrow = fd * 16 + l15;
        bf16x8 vf = *(const bf16x8*)(Vb + vrow * 64 + ((slotbase ^ (vrow & 7)) * 8));
        Of[fd] = MFMA16(vf, pu.v, Of[fd]);  // O^T = V^T * P^T (k-permuted both sides)
      }
      __builtin_amdgcn_s_setprio(0);
    }
  };

  stage(0, 0);
  int cur = 0;
  for (int kt = 0; kt < 14; ++kt) {  // full tiles, no masking
    stage(kt + 1, cur ^ 1);
    asm volatile("s_waitcnt vmcnt(4)" ::: "memory");
    asm volatile("s_barrier" ::: "memory");
    tilecomp(K_lds[cur], V_lds[cur], false);
    asm volatile("s_barrier" ::: "memory");
    cur ^= 1;
  }
  asm volatile("s_waitcnt vmcnt(0)" ::: "memory");
  asm volatile("s_barrier" ::: "memory");
  tilecomp(K_lds[cur], V_lds[cur], true);

  const int bq = bh / HH, hq = bh - bq * HH;
  const int lq = w * 16 + l15;
  if (lq < qn) {
    float inv = 1.0f / l_run;
    size_t rowo = ((size_t)(bq * NN + q0 + lq)) * CC + hq * 64;
#pragma unroll
    for (int fd = 0; fd < 4; ++fd) {
      uint2 st;
      st.x = pack2(Of[fd][0] * inv, Of[fd][1] * inv);
      st.y = pack2(Of[fd][2] * inv, Of[fd][3] * inv);
      *(uint2*)(AO + rowo + fd * 16 + hi * 4) = st;
    }
  }
}

// ---------------- output projection GEMM + bias (fp32 out) ----------------
__global__ __launch_bounds__(256, 2) void gemm_out(
    const __bf16* __restrict__ AO, const __bf16* __restrict__ WPt,
    const float* __restrict__ bias, float* __restrict__ Out) {
  __shared__ alignas(16) __bf16 L[2 * 16384];
  int nt = blockIdx.x, mt = blockIdx.y;
  int m0 = mt * 128, nc = nt * 128;
  const __bf16* bt = WPt + (size_t)nc * CC;
  f32x4 acc[4][4] = {};
  gemm_core_db2(AO, bt, L, m0, MTOK, acc);

  const int tid = threadIdx.x;
  const int w = tid >> 6, l = tid & 63, l15 = l & 15, hi = l >> 4;
  const int wr = (w >> 1) * 64, wc = (w & 1) * 64;
#pragma unroll
  for (int mf = 0; mf < 4; ++mf) {
#pragma unroll
    for (int r = 0; r < 4; ++r) {
      int token = m0 + wr + mf * 16 + hi * 4 + r;
      if (token >= MTOK) continue;
#pragma unroll
      for (int nf = 0; nf < 4; ++nf) {
        int col = nc + wc + nf * 16 + l15;
        Out[(size_t)token * CC + col] = acc[mf][nf][r] + bias[col];
      }
    }
  }
}

extern "C" void kernel_launch(void* const* d_in, const int* in_sizes, int n_in,
                              void* d_out, int out_size, void* d_ws, size_t ws_size,
                              hipStream_t stream) {
  (void)in_sizes; (void)n_in; (void)out_size;
  const float* x   = (const float*)d_in[0];
  const float* Wq  = (const float*)d_in[1];
  const float* Wk  = (const float*)d_in[2];
  const float* Wv  = (const float*)d_in[3];
  const float* Wvc = (const float*)d_in[4];
  const float* Wp  = (const float*)d_in[5];
  const float* bp  = (const float*)d_in[6];
  float* out = (float*)d_out;

  const size_t SZ_TOK = (size_t)TOKC * 2;
  const size_t SZ_W   = (size_t)CC * CC * 2;
  const size_t NEED   = SZ_TOK * 6 + SZ_W * 5;
  if (ws_size < NEED) return;

  char* ws = (char*)d_ws;
  __bf16* xb  = (__bf16*)ws;
  __bf16* wt  = (__bf16*)(ws + SZ_TOK);
  __bf16* qb  = (__bf16*)(ws + SZ_TOK + 5 * SZ_W);
  __bf16* kb  = qb + TOKC;
  __bf16* vab = kb + TOKC;
  __bf16* vvb = vab + TOKC;
  __bf16* aob = vvb + TOKC;

  cvt_x_kernel<<<TOKC / (256 * 8), 256, 0, stream>>>(x, xb);
  cvt_w_kernel<<<dim3(24, 24, 5), 256, 0, stream>>>(Wq, Wk, Wv, Wvc, Wp, wt);
  gemm_qkv256<<<dim3(12, 57), 512, 0, stream>>>(xb, wt, qb, kb, vab, vvb);
  attn_kernel<<<dim3(16, 192), 256, 0, stream>>>(qb, kb, vab, vvb, aob);
  gemm_out<<<dim3(6, 114), 256, 0, stream>>>(aob, wt + 4 * (size_t)(CC * CC), bp, out);
}

// Round 10
// 253.711 us; speedup vs baseline: 1.1192x; 1.1192x over previous
//
#include <hip/hip_runtime.h>

typedef __attribute__((ext_vector_type(8))) __bf16 bf16x8;
typedef __attribute__((ext_vector_type(4))) float f32x4;

constexpr int BB = 16, NN = 906, CC = 768, HH = 12, MM1 = 513;
constexpr int MTOK = BB * NN;      // 14496 tokens
constexpr int TOKC = MTOK * CC;    // 11132928 elements

#define MFMA16(a, b, c) __builtin_amdgcn_mfma_f32_16x16x32_bf16((a), (b), (c), 0, 0, 0)

__device__ __forceinline__ void glds16(const void* g, void* l) {
  __builtin_amdgcn_global_load_lds(
      (const __attribute__((address_space(1))) void*)g,
      (__attribute__((address_space(3))) void*)l, 16, 0, 0);
}

__device__ __forceinline__ unsigned pack2(float a, float b) {
  unsigned short ua = __builtin_bit_cast(unsigned short, (__bf16)a);
  unsigned short ub = __builtin_bit_cast(unsigned short, (__bf16)b);
  return (unsigned)ua | ((unsigned)ub << 16);
}

union U8 { unsigned u[4]; bf16x8 v; };

// ---------------- convert x (fp32 -> bf16) ----------------
__global__ __launch_bounds__(256) void cvt_x_kernel(const float* __restrict__ x,
                                                    __bf16* __restrict__ xb) {
  long i = (long)blockIdx.x * 256 + threadIdx.x;
  const float4* p = (const float4*)x + i * 2;
  float4 a = p[0], b = p[1];
  bf16x8 o;
  o[0] = (__bf16)a.x; o[1] = (__bf16)a.y; o[2] = (__bf16)a.z; o[3] = (__bf16)a.w;
  o[4] = (__bf16)b.x; o[5] = (__bf16)b.y; o[6] = (__bf16)b.z; o[7] = (__bf16)b.w;
  *(bf16x8*)(xb + i * 8) = o;
}

// ---------------- transpose + convert weights: Wt[n][k] = W[k][n] ----------------
__global__ __launch_bounds__(256) void cvt_w_kernel(
    const float* __restrict__ W0, const float* __restrict__ W1,
    const float* __restrict__ W2, const float* __restrict__ W3,
    const float* __restrict__ W4, __bf16* __restrict__ out) {
  __shared__ float t[32][33];
  int z = blockIdx.z;
  const float* src = z == 0 ? W0 : z == 1 ? W1 : z == 2 ? W2 : z == 3 ? W3 : W4;
  __bf16* dst = out + (size_t)z * CC * CC;
  int x0 = blockIdx.x * 32, y0 = blockIdx.y * 32;
  int tx = threadIdx.x & 31, ty = threadIdx.x >> 5;  // ty 0..7
#pragma unroll
  for (int i = 0; i < 4; ++i)
    t[ty + i * 8][tx] = src[(size_t)(y0 + ty + i * 8) * CC + x0 + tx];
  __syncthreads();
#pragma unroll
  for (int i = 0; i < 4; ++i)
    dst[(size_t)(x0 + ty + i * 8) * CC + y0 + tx] = (__bf16)t[tx][ty + i * 8];
}

// -- Schedule-B 128x128x768 GEMM mainloop: 2 LDS buffers (64 KB, 2 blocks/CU), --
// -- counted vmcnt(8), full-iteration prefetch distance, 2 barriers/iter.      --
__device__ __forceinline__ void gemm_core_db2(const __bf16* __restrict__ A,
                                              const __bf16* __restrict__ Bt,
                                              __bf16* __restrict__ L,
                                              int m0, int M, f32x4 acc[4][4]) {
  const int tid = threadIdx.x;
  const int w = tid >> 6, l = tid & 63;
  const int l15 = l & 15, hi = l >> 4;
  const int wr = (w >> 1) * 64, wc = (w & 1) * 64;
  const int srow = l >> 3, sslot = l & 7;

  const __bf16* ga[4]; const __bf16* gb[4]; int lofs[4];
#pragma unroll
  for (int rr = 0; rr < 4; ++rr) {
    int row = rr * 32 + w * 8 + srow;
    int co = (sslot ^ (row & 7)) * 8;
    int arow = m0 + row; arow = arow < M ? arow : M - 1;
    ga[rr] = A + (size_t)arow * CC + co;
    gb[rr] = Bt + (size_t)row * CC + co;
    lofs[rr] = row * 64 + sslot * 8;
  }

#define STAGE_(buf)                                                            \
  {                                                                            \
    _Pragma("unroll") for (int rr = 0; rr < 4; ++rr) {                         \
      glds16(ga[rr], L + (buf) * 16384 + lofs[rr]);                            \
      glds16(gb[rr], L + (buf) * 16384 + 8192 + lofs[rr]);                     \
      ga[rr] += 64; gb[rr] += 64;                                              \
    }                                                                          \
  }

#define COMP_(buf)                                                             \
  {                                                                            \
    _Pragma("unroll") for (int kks = 0; kks < 2; ++kks) {                      \
      bf16x8 af[4], bfr[4];                                                    \
      _Pragma("unroll") for (int mf = 0; mf < 4; ++mf) {                       \
        int rowa = wr + mf * 16 + l15;                                         \
        af[mf] = *(const bf16x8*)(L + (buf) * 16384 + rowa * 64 +              \
                                  (((kks * 4 + hi) ^ (rowa & 7)) * 8));        \
      }                                                                        \
      _Pragma("unroll") for (int nf = 0; nf < 4; ++nf) {                       \
        int rowb = wc + nf * 16 + l15;                                         \
        bfr[nf] = *(const bf16x8*)(L + (buf) * 16384 + 8192 + rowb * 64 +      \
                                   (((kks * 4 + hi) ^ (rowb & 7)) * 8));       \
      }                                                                        \
      __builtin_amdgcn_s_setprio(1);                                           \
      _Pragma("unroll") for (int mf = 0; mf < 4; ++mf)                         \
          _Pragma("unroll") for (int nf = 0; nf < 4; ++nf)                     \
              acc[mf][nf] = MFMA16(af[mf], bfr[nf], acc[mf][nf]);              \
      __builtin_amdgcn_s_setprio(0);                                           \
    }                                                                          \
  }

  STAGE_(0);  // tile 0 -> 8 loads in flight

#pragma unroll
  for (int t = 0; t < 12; ++t) {
    if (t < 11) {
      STAGE_((t + 1) & 1);  // now 16 in flight
      asm volatile("s_waitcnt vmcnt(8)" ::: "memory");  // retire tile t only
    } else {
      asm volatile("s_waitcnt vmcnt(0)" ::: "memory");
    }
    asm volatile("s_barrier" ::: "memory");
    COMP_(t & 1);
    asm volatile("s_barrier" ::: "memory");  // close reads before next overwrite
  }
#undef STAGE_
#undef COMP_
}

// ---------------- QKV(+Vc) projection GEMM ----------------
// q pre-scaled by d^-1/2 * log2(e) so attention can use native exp2.
__global__ __launch_bounds__(256, 2) void gemm_qkv(
    const __bf16* __restrict__ Xb, const __bf16* __restrict__ WT,
    __bf16* __restrict__ Qb, __bf16* __restrict__ Kb,
    __bf16* __restrict__ VAb, __bf16* __restrict__ VVb) {
  __shared__ alignas(16) __bf16 L[2 * 16384];
  int nt = blockIdx.x, mt = blockIdx.y;
  int m0 = mt * 128;
  int wi = nt / 6, nc = (nt % 6) * 128;
  const __bf16* bt = WT + (size_t)wi * (CC * CC) + (size_t)nc * CC;
  f32x4 acc[4][4] = {};
  gemm_core_db2(Xb, bt, L, m0, MTOK, acc);

  const int tid = threadIdx.x;
  const int w = tid >> 6, l = tid & 63, l15 = l & 15, hi = l >> 4;
  const int wr = (w >> 1) * 64, wc = (w & 1) * 64;
  const float qs = (wi == 0) ? 0.1803368801f : 1.0f;  // 0.125 * log2(e)
#pragma unroll
  for (int mf = 0; mf < 4; ++mf) {
#pragma unroll
    for (int r = 0; r < 4; ++r) {
      int token = m0 + wr + mf * 16 + hi * 4 + r;
      if (token >= MTOK) continue;
      int b = token / NN, n = token - b * NN;
#pragma unroll
      for (int nf = 0; nf < 4; ++nf) {
        int col = nc + wc + nf * 16 + l15;
        int h = col >> 6, dd = col & 63;
        __bf16 bv = (__bf16)(acc[mf][nf][r] * qs);
        size_t bhd = (size_t)(b * HH + h);
        if (wi == 0)      Qb[(bhd * NN + n) * 64 + dd] = bv;
        else if (wi == 1) Kb[(bhd * NN + n) * 64 + dd] = bv;
        else if (wi == 2) ((n < MM1) ? VAb : VVb)[(bhd * 64 + dd) * NN + n] = bv;
        else              ((n < MM1) ? VVb : VAb)[(bhd * 64 + dd) * NN + n] = bv;
      }
    }
  }
}

// ---- flash attention: 128-row q-tiles, 32 rows/wave (2 groups), K/V frag reuse ----
// Swapped QK^T, unnormalized exp2 softmax (scores bounded), in-register P.
// K-frags and V-frags read ONCE per wave per tile and reused across both q-groups:
// 32 MFMA per 16 ds_read_b128 (2x the old ratio). Tile 4 (rows 512..639) straddles
// the 513 modality boundary: stage BOTH VV (main) and VA (aux), split P per lane
// into mod1/mod2 columns (P = Pa + Pv), O += VV*Pv + VA*Pa. Block-uniform branch.
__global__ __launch_bounds__(256, 2) void attn_kernel(
    const __bf16* __restrict__ Q, const __bf16* __restrict__ K,
    const __bf16* __restrict__ VA, const __bf16* __restrict__ VV,
    __bf16* __restrict__ AO) {
  __shared__ alignas(16) __bf16 K_lds[2][64 * 64];
  __shared__ alignas(16) __bf16 V_lds[2][64 * 64];   // [dd][key] main
  __shared__ alignas(16) __bf16 VX_lds[2][64 * 64];  // [dd][key] aux (straddle only)

  const int tid = threadIdx.x;
  const int w = tid >> 6, l = tid & 63;
  const int l15 = l & 15, hi = l >> 4;
  const int bh = blockIdx.y, tile = blockIdx.x;

  const int q0 = tile * 128;
  const int qn = min(128, NN - q0);
  const bool straddle = (tile == 4);           // rows 512..639: 1 mod1 + 127 mod2

  const __bf16* qp = Q + (size_t)bh * NN * 64;
  const __bf16* kp = K + (size_t)bh * NN * 64;
  const __bf16* vmain = ((tile < 4) ? VA : VV) + (size_t)bh * 64 * NN;
  const __bf16* vaux  = VA + (size_t)bh * 64 * NN;

  // Q fragments: 2 groups x 2 k-halves
  bf16x8 qf[2][2];
#pragma unroll
  for (int g = 0; g < 2; ++g) {
    int qrow = q0 + w * 32 + g * 16 + l15; qrow = qrow < NN ? qrow : NN - 1;
    qf[g][0] = *(const bf16x8*)(qp + (size_t)qrow * 64 + hi * 8);
    qf[g][1] = *(const bf16x8*)(qp + (size_t)qrow * 64 + 32 + hi * 8);
  }

  f32x4 Of[2][4] = {};
  float l_run[2] = {0.f, 0.f};

  const int srow = l >> 3, sslot = l & 7;
  auto stage = [&](int kt, int buf) {
    int k0s = kt * 64;
#pragma unroll
    for (int rr = 0; rr < 2; ++rr) {
      int row = rr * 32 + w * 8 + srow;
      int krow = k0s + row; krow = krow < NN ? krow : NN - 1;  // dup key, masked
      glds16(kp + (size_t)krow * 64 + ((sslot ^ (row & 7)) * 8),
             &K_lds[buf][row * 64 + sslot * 8]);
      int vcol = k0s + ((sslot ^ (row & 7)) * 8);  // tail overrun: P=0 for those keys
      glds16(vmain + (size_t)row * NN + vcol, &V_lds[buf][row * 64 + sslot * 8]);
      if (straddle)
        glds16(vaux + (size_t)row * NN + vcol, &VX_lds[buf][row * 64 + sslot * 8]);
    }
  };

  const bool ofirst = ((hi & 1) == 0);
  auto tilecomp = [&](int cur, bool maskTail) {
    const __bf16* Kb = K_lds[cur];
    const __bf16* Vb = V_lds[cur];
    const __bf16* Xb = VX_lds[cur];

    // K fragments once, reused for both q-groups
    bf16x8 kf[2][4];
#pragma unroll
    for (int kks = 0; kks < 2; ++kks)
#pragma unroll
      for (int f = 0; f < 4; ++f) {
        int rk = f * 16 + l15;
        kf[kks][f] = *(const bf16x8*)(Kb + rk * 64 + (((kks * 4 + hi) ^ (rk & 7)) * 8));
      }

    f32x4 sa[2][4] = {};
    __builtin_amdgcn_s_setprio(1);
#pragma unroll
    for (int g = 0; g < 2; ++g)
#pragma unroll
      for (int kks = 0; kks < 2; ++kks)
#pragma unroll
        for (int f = 0; f < 4; ++f)
          sa[g][f] = MFMA16(kf[kks][f], qf[g][kks], sa[g][f]);
    __builtin_amdgcn_s_setprio(0);

    if (maskTail) {
#pragma unroll
      for (int f = 0; f < 4; ++f) {
        int keyb = 896 + f * 16 + hi * 4;
#pragma unroll
        for (int r = 0; r < 4; ++r)
          if (keyb + r >= NN) { sa[0][f][r] = -1e30f; sa[1][f][r] = -1e30f; }
      }
    }

    // p = exp2(s) in place; row-sums via 2 shuffles per group
#pragma unroll
    for (int g = 0; g < 2; ++g) {
      float sl = 0.f;
#pragma unroll
      for (int f = 0; f < 4; ++f)
#pragma unroll
        for (int r = 0; r < 4; ++r) {
          sa[g][f][r] = __builtin_amdgcn_exp2f(sa[g][f][r]);
          sl += sa[g][f][r];
        }
      sl += __shfl_xor(sl, 16);
      sl += __shfl_xor(sl, 32);
      l_run[g] += sl;
    }

#pragma unroll
    for (int c = 0; c < 2; ++c) {
      U8 pu[2];
#pragma unroll
      for (int g = 0; g < 2; ++g) {
        unsigned p00 = pack2(sa[g][c * 2][0], sa[g][c * 2][1]);
        unsigned p01 = pack2(sa[g][c * 2][2], sa[g][c * 2][3]);
        unsigned p10 = pack2(sa[g][c * 2 + 1][0], sa[g][c * 2 + 1][1]);
        unsigned p11 = pack2(sa[g][c * 2 + 1][2], sa[g][c * 2 + 1][3]);
        unsigned own0 = (hi & 1) ? p10 : p00;
        unsigned own1 = (hi & 1) ? p11 : p01;
        unsigned snd0 = (hi & 1) ? p00 : p10;
        unsigned snd1 = (hi & 1) ? p01 : p11;
        unsigned rcv0 = __shfl_xor(snd0, 16);
        unsigned rcv1 = __shfl_xor(snd1, 16);
        pu[g].u[0] = ofirst ? own0 : rcv0;
        pu[g].u[1] = ofirst ? own1 : rcv1;
        pu[g].u[2] = ofirst ? rcv0 : own0;
        pu[g].u[3] = ofirst ? rcv1 : own1;
      }
      const int slotbase = c * 4 + (hi & 1) * 2 + (hi >> 1);  // V octet slot
      if (!straddle) {
        __builtin_amdgcn_s_setprio(1);
#pragma unroll
        for (int fd = 0; fd < 4; ++fd) {
          int vrow = fd * 16 + l15;
          bf16x8 vf = *(const bf16x8*)(Vb + vrow * 64 + ((slotbase ^ (vrow & 7)) * 8));
#pragma unroll
          for (int g = 0; g < 2; ++g)
            Of[g][fd] = MFMA16(vf, pu[g].v, Of[g][fd]);
        }
        __builtin_amdgcn_s_setprio(0);
      } else {
        // split P columns by query modality: q = q0 + w*32 + g*16 + l15
        U8 pua[2], puv[2];
#pragma unroll
        for (int g = 0; g < 2; ++g) {
          bool m1 = (q0 + w * 32 + g * 16 + l15) < MM1;
#pragma unroll
          for (int i = 0; i < 4; ++i) {
            pua[g].u[i] = m1 ? pu[g].u[i] : 0u;
            puv[g].u[i] = m1 ? 0u : pu[g].u[i];
          }
        }
        __builtin_amdgcn_s_setprio(1);
#pragma unroll
        for (int fd = 0; fd < 4; ++fd) {
          int vrow = fd * 16 + l15;
          int vo = vrow * 64 + ((slotbase ^ (vrow & 7)) * 8);
          bf16x8 vf = *(const bf16x8*)(Vb + vo);
          bf16x8 xf = *(const bf16x8*)(Xb + vo);
#pragma unroll
          for (int g = 0; g < 2; ++g) {
            Of[g][fd] = MFMA16(vf, puv[g].v, Of[g][fd]);
            Of[g][fd] = MFMA16(xf, pua[g].v, Of[g][fd]);
          }
        }
        __builtin_amdgcn_s_setprio(0);
      }
    }
  };

  stage(0, 0);
  int cur = 0;
  for (int kt = 0; kt < 14; ++kt) {  // full tiles, no masking
    stage(kt + 1, cur ^ 1);
    if (straddle) {
      asm volatile("s_waitcnt vmcnt(6)" ::: "memory");
    } else {
      asm volatile("s_waitcnt vmcnt(4)" ::: "memory");
    }
    asm volatile("s_barrier" ::: "memory");
    tilecomp(cur, false);
    asm volatile("s_barrier" ::: "memory");
    cur ^= 1;
  }
  asm volatile("s_waitcnt vmcnt(0)" ::: "memory");
  asm volatile("s_barrier" ::: "memory");
  tilecomp(cur, true);

  const int bq = bh / HH, hq = bh - bq * HH;
#pragma unroll
  for (int g = 0; g < 2; ++g) {
    int lq = w * 32 + g * 16 + l15;
    if (lq >= qn) continue;
    float inv = 1.0f / l_run[g];
    size_t rowo = ((size_t)(bq * NN + q0 + lq)) * CC + hq * 64;
#pragma unroll
    for (int fd = 0; fd < 4; ++fd) {
      uint2 st;
      st.x = pack2(Of[g][fd][0] * inv, Of[g][fd][1] * inv);
      st.y = pack2(Of[g][fd][2] * inv, Of[g][fd][3] * inv);
      *(uint2*)(AO + rowo + fd * 16 + hi * 4) = st;
    }
  }
}

// ---------------- output projection GEMM + bias (fp32 out) ----------------
__global__ __launch_bounds__(256, 2) void gemm_out(
    const __bf16* __restrict__ AO, const __bf16* __restrict__ WPt,
    const float* __restrict__ bias, float* __restrict__ Out) {
  __shared__ alignas(16) __bf16 L[2 * 16384];
  int nt = blockIdx.x, mt = blockIdx.y;
  int m0 = mt * 128, nc = nt * 128;
  const __bf16* bt = WPt + (size_t)nc * CC;
  f32x4 acc[4][4] = {};
  gemm_core_db2(AO, bt, L, m0, MTOK, acc);

  const int tid = threadIdx.x;
  const int w = tid >> 6, l = tid & 63, l15 = l & 15, hi = l >> 4;
  const int wr = (w >> 1) * 64, wc = (w & 1) * 64;
#pragma unroll
  for (int mf = 0; mf < 4; ++mf) {
#pragma unroll
    for (int r = 0; r < 4; ++r) {
      int token = m0 + wr + mf * 16 + hi * 4 + r;
      if (token >= MTOK) continue;
#pragma unroll
      for (int nf = 0; nf < 4; ++nf) {
        int col = nc + wc + nf * 16 + l15;
        Out[(size_t)token * CC + col] = acc[mf][nf][r] + bias[col];
      }
    }
  }
}

extern "C" void kernel_launch(void* const* d_in, const int* in_sizes, int n_in,
                              void* d_out, int out_size, void* d_ws, size_t ws_size,
                              hipStream_t stream) {
  (void)in_sizes; (void)n_in; (void)out_size;
  const float* x   = (const float*)d_in[0];
  const float* Wq  = (const float*)d_in[1];
  const float* Wk  = (const float*)d_in[2];
  const float* Wv  = (const float*)d_in[3];
  const float* Wvc = (const float*)d_in[4];
  const float* Wp  = (const float*)d_in[5];
  const float* bp  = (const float*)d_in[6];
  float* out = (float*)d_out;

  const size_t SZ_TOK = (size_t)TOKC * 2;
  const size_t SZ_W   = (size_t)CC * CC * 2;
  const size_t NEED   = SZ_TOK * 6 + SZ_W * 5;
  if (ws_size < NEED) return;

  char* ws = (char*)d_ws;
  __bf16* xb  = (__bf16*)ws;
  __bf16* wt  = (__bf16*)(ws + SZ_TOK);
  __bf16* qb  = (__bf16*)(ws + SZ_TOK + 5 * SZ_W);
  __bf16* kb  = qb + TOKC;
  __bf16* vab = kb + TOKC;
  __bf16* vvb = vab + TOKC;
  __bf16* aob = vvb + TOKC;

  cvt_x_kernel<<<TOKC / (256 * 8), 256, 0, stream>>>(x, xb);
  cvt_w_kernel<<<dim3(24, 24, 5), 256, 0, stream>>>(Wq, Wk, Wv, Wvc, Wp, wt);
  gemm_qkv<<<dim3(24, 114), 256, 0, stream>>>(xb, wt, qb, kb, vab, vvb);
  attn_kernel<<<dim3(8, 192), 256, 0, stream>>>(qb, kb, vab, vvb, aob);
  gemm_out<<<dim3(6, 114), 256, 0, stream>>>(aob, wt + 4 * (size_t)(CC * CC), bp, out);
}